// Round 16
// baseline (24.190 us; speedup 1.0000x reference)
//
#include <hip/hip_runtime.h>

// Sequential implicit-midpoint solve: y_k = y_{k-1} + DT*f_k - DT*tanh(W s_k),
// s_k = (y_k + y_{k-1})/2, one wave per batch element.
//
// R16: layout-invariant MFMA loop — ZERO LDS memory traffic.
// Key identity: with D = W*S (A-operand = W), lane l's D output (tile t,
// reg j) = u_{chain l&15}[comp 16t+4*(l>>4)+j], which is EXACTLY the
// residency the next round's B-operand needs. So the state stays put:
//   lane l: chain position c = l&15 (c=0..3 steps k..k+3, c=4 preview),
//           comp set P(g) = {16h+4g+kk}, g = l>>4.
// Cross-chain recurrences = DPP row_shr prefix sums over the 16-lane row:
//   s_c = yprev + DT*(F_c - 0.5 f_c) - DT*(c+0.5)*tcar   (F = prefix of f)
//   y_{k+c} = yprev + Y_c,  Y = prefix of delta_c = DT*(f_c - tanh_c)
// Residual cross-lane: broadcast Y_3 (f32) and preview tanh (f16x2) from
// row positions 3/4 via ds_swizzle (lane' = (lane&0x10)|pos); the swizzles
// are issued at round end and consumed after next round's f-prefix, hiding
// their latency. R15's two LDS write->fence->read trips (~55% of the round
// on a solo wave) are gone entirely.
// W pre-scaled by 2*log2(e): tanh(Ws) = 1 - 2/(exp2(u)+1). R13 numerics.

#define SDIM 64
#define DT_C 0.05f
#define WSCALE 2.8853900817779268f  // 2*log2(e)

typedef _Float16 v4h __attribute__((ext_vector_type(4)));
typedef float    v4f __attribute__((ext_vector_type(4)));
typedef __fp16   g2  __attribute__((ext_vector_type(2)));

#if defined(__HIP_DEVICE_COMPILE__)
#define MFMA16(A, B, C) __builtin_amdgcn_mfma_f32_16x16x16f16((A), (B), (C), 0, 0, 0)
#else
#define MFMA16(A, B, C) (C)  // host pass parses only
#endif

union H2U  { int i; g2 g; };
union V4HU { int2 i2; v4h h; g2 g[2]; };

__device__ __forceinline__ float recip_fast(float x) {
    float r; asm("v_rcp_f32 %0, %1" : "=v"(r) : "v"(x)); return r;
}
__device__ __forceinline__ float exp2_fast(float x) {
    float r; asm("v_exp_f32 %0, %1" : "=v"(r) : "v"(x)); return r;
}
__device__ __forceinline__ int pack_h2i(float a, float b) {
    H2U u; u.g = __builtin_amdgcn_cvt_pkrtz(a, b); return u.i;
}
__device__ __forceinline__ v4h pack_h4(float a, float b, float c, float d) {
    V4HU u;
    u.g[0] = __builtin_amdgcn_cvt_pkrtz(a, b);
    u.g[1] = __builtin_amdgcn_cvt_pkrtz(c, d);
    return u.h;
}

// inclusive prefix-sum across the 16-lane DPP row (exact for positions 0..7;
// chains use 0..4). old=0 + bound_ctrl: OOB contributes 0 either way.
#define PFX3(arr)                                                          \
    {                                                                      \
        _Pragma("unroll")                                                  \
        for (int _i = 0; _i < 16; ++_i)                                    \
            arr[_i] += __int_as_float(__builtin_amdgcn_update_dpp(         \
                0, __float_as_int(arr[_i]), 0x111, 0xF, 0xF, true));       \
        _Pragma("unroll")                                                  \
        for (int _i = 0; _i < 16; ++_i)                                    \
            arr[_i] += __int_as_float(__builtin_amdgcn_update_dpp(         \
                0, __float_as_int(arr[_i]), 0x112, 0xF, 0xF, true));       \
        _Pragma("unroll")                                                  \
        for (int _i = 0; _i < 16; ++_i)                                    \
            arr[_i] += __int_as_float(__builtin_amdgcn_update_dpp(         \
                0, __float_as_int(arr[_i]), 0x114, 0xF, 0xF, true));       \
    }

// 16 MFMAs: acc_t += sum_h wa[t*4+h] * bf[h]
#define MFMA_BLOCK(ac0, ac1, ac2, ac3, wa, bf)                             \
    ac0 = MFMA16(wa[0],  bf[0], ac0);  ac1 = MFMA16(wa[4],  bf[0], ac1);   \
    ac2 = MFMA16(wa[8],  bf[0], ac2);  ac3 = MFMA16(wa[12], bf[0], ac3);   \
    ac0 = MFMA16(wa[1],  bf[1], ac0);  ac1 = MFMA16(wa[5],  bf[1], ac1);   \
    ac2 = MFMA16(wa[9],  bf[1], ac2);  ac3 = MFMA16(wa[13], bf[1], ac3);   \
    ac0 = MFMA16(wa[2],  bf[2], ac0);  ac1 = MFMA16(wa[6],  bf[2], ac1);   \
    ac2 = MFMA16(wa[10], bf[2], ac2);  ac3 = MFMA16(wa[14], bf[2], ac3);   \
    ac0 = MFMA16(wa[3],  bf[3], ac0);  ac1 = MFMA16(wa[7],  bf[3], ac1);   \
    ac2 = MFMA16(wa[11], bf[3], ac2);  ac3 = MFMA16(wa[15], bf[3], ac3)

__global__ __launch_bounds__(64) void rnes_inv_kernel(
    const float* __restrict__ y0,
    const float* __restrict__ forces,
    const float* __restrict__ W,
    float* __restrict__ out,
    int n, int B)
{
    const int b = blockIdx.x;
    const int l = threadIdx.x;
    const int c = l & 15;   // chain/row position
    const int g = l >> 4;   // comp group: comps 16h + 4g + kk

    // A-operand frags (D = W*S): wa[t*4+h] holds W[16t+c][16h+4g+kk], scaled.
    // (Identical indexing to R15's verified wb load.)
    v4h wa[16];
    {
        #pragma unroll
        for (int t = 0; t < 4; ++t) {
            #pragma unroll
            for (int h = 0; h < 4; ++h) {
                const float4 v = *reinterpret_cast<const float4*>(
                    W + (16 * t + c) * 64 + 16 * h + 4 * g);
                wa[t * 4 + h] = pack_h4(WSCALE * v.x, WSCALE * v.y,
                                        WSCALE * v.z, WSCALE * v.w);
            }
        }
    }

    const size_t stride = (size_t)B * SDIM;
    const int cbase = b * SDIM + 4 * g;   // + 16h + kk

    // per-comp state for this lane's 16 comps (j = 4h+kk -> comp 16h+4g+kk)
    float yprev[16], tcar[16], fcur[16];

    #pragma unroll
    for (int h = 0; h < 4; ++h) {
        const float4 v = *reinterpret_cast<const float4*>(y0 + cbase + 16 * h);
        yprev[4 * h + 0] = v.x; yprev[4 * h + 1] = v.y;
        yprev[4 * h + 2] = v.z; yprev[4 * h + 3] = v.w;
    }
    if (c == 0) {  // out[0] = y0 pass-through (one row's worth per g)
        #pragma unroll
        for (int h = 0; h < 4; ++h) {
            float4 st;
            st.x = yprev[4 * h + 0]; st.y = yprev[4 * h + 1];
            st.z = yprev[4 * h + 2]; st.w = yprev[4 * h + 3];
            *reinterpret_cast<float4*>(out + cbase + 16 * h) = st;
        }
    }

    // ---- seed: tcar = tanh(W y0) (all B-cols identical -> own col valid) ----
    {
        v4h bf[4];
        #pragma unroll
        for (int h = 0; h < 4; ++h)
            bf[h] = pack_h4(yprev[4 * h + 0], yprev[4 * h + 1],
                            yprev[4 * h + 2], yprev[4 * h + 3]);
        v4f ac0 = {0.f, 0.f, 0.f, 0.f}, ac1 = ac0, ac2 = ac0, ac3 = ac0;
        MFMA_BLOCK(ac0, ac1, ac2, ac3, wa, bf);
        #pragma unroll
        for (int j = 0; j < 4; ++j) {
            tcar[0  + j] = fmaf(-2.f, recip_fast(exp2_fast(ac0[j]) + 1.f), 1.f);
            tcar[4  + j] = fmaf(-2.f, recip_fast(exp2_fast(ac1[j]) + 1.f), 1.f);
            tcar[8  + j] = fmaf(-2.f, recip_fast(exp2_fast(ac2[j]) + 1.f), 1.f);
            tcar[12 + j] = fmaf(-2.f, recip_fast(exp2_fast(ac3[j]) + 1.f), 1.f);
        }
    }

    // pending broadcast regs (seed: yprev-increment 0; tcar pass-through)
    int swY[16], swT[8];
    #pragma unroll
    for (int j = 0; j < 16; ++j) swY[j] = 0;
    #pragma unroll
    for (int i = 0; i < 8; ++i) swT[i] = pack_h2i(tcar[2 * i], tcar[2 * i + 1]);

    // first round's forces: lane c loads f_{1+c} (c<=4)
    {
        const bool a0 = (c <= 4) && (1 + c < n);
        #pragma unroll
        for (int j = 0; j < 16; ++j) fcur[j] = 0.f;
        if (a0) {
            const float* fp = forces + (size_t)(1 + c) * stride + cbase;
            #pragma unroll
            for (int h = 0; h < 4; ++h) {
                const float4 v = *reinterpret_cast<const float4*>(fp + 16 * h);
                fcur[4 * h + 0] = v.x; fcur[4 * h + 1] = v.y;
                fcur[4 * h + 2] = v.z; fcur[4 * h + 3] = v.w;
            }
        }
    }

    const float coef = DT_C * ((float)c + 0.5f);

    #pragma unroll 1
    for (int k = 1; k < n; k += 4) {
        // 1. prefetch next round's forces (lane c -> f_{k+4+c})
        float fnext[16];
        {
            const bool a2 = (c <= 4) && (k + 4 + c < n);
            #pragma unroll
            for (int j = 0; j < 16; ++j) fnext[j] = 0.f;
            if (a2) {
                const float* fp = forces + (size_t)(k + 4 + c) * stride + cbase;
                #pragma unroll
                for (int h = 0; h < 4; ++h) {
                    const float4 v = *reinterpret_cast<const float4*>(fp + 16 * h);
                    fnext[4 * h + 0] = v.x; fnext[4 * h + 1] = v.y;
                    fnext[4 * h + 2] = v.z; fnext[4 * h + 3] = v.w;
                }
            }
        }

        // 2. F = row-prefix of masked f (no tcar/yprev dependency ->
        //    overlaps the pending ds_swizzle latency)
        const bool act = (c <= 4) && (k + c < n);
        float fh[16], F[16];
        #pragma unroll
        for (int j = 0; j < 16; ++j) { fh[j] = act ? fcur[j] : 0.f; F[j] = fh[j]; }
        PFX3(F);

        // 3. apply pending broadcasts (compiler places the lgkm wait here)
        #pragma unroll
        for (int j = 0; j < 16; ++j) yprev[j] += __int_as_float(swY[j]);
        #pragma unroll
        for (int i = 0; i < 8; ++i) {
            H2U u_; u_.i = swT[i];
            tcar[2 * i + 0] = (float)u_.g[0];
            tcar[2 * i + 1] = (float)u_.g[1];
        }

        // 4. speculative midpoints: s_c = yprev + DT*(F_c - 0.5 f_c) - DT(c+.5) tcar
        v4h bf[4];
        #pragma unroll
        for (int h = 0; h < 4; ++h) {
            float sv[4];
            #pragma unroll
            for (int kk = 0; kk < 4; ++kk) {
                const int j = 4 * h + kk;
                sv[kk] = fmaf(DT_C, F[j] - 0.5f * fh[j], yprev[j]) - coef * tcar[j];
            }
            bf[h] = pack_h4(sv[0], sv[1], sv[2], sv[3]);
        }

        // 5. MFMA: u_c[comps] lands in this lane's accs
        v4f ac0 = {0.f, 0.f, 0.f, 0.f}, ac1 = ac0, ac2 = ac0, ac3 = ac0;
        MFMA_BLOCK(ac0, ac1, ac2, ac3, wa, bf);

        // 6. fresh tanh per chain
        float th[16];
        #pragma unroll
        for (int j = 0; j < 4; ++j) {
            th[0  + j] = fmaf(-2.f, recip_fast(exp2_fast(ac0[j]) + 1.f), 1.f);
            th[4  + j] = fmaf(-2.f, recip_fast(exp2_fast(ac1[j]) + 1.f), 1.f);
            th[8  + j] = fmaf(-2.f, recip_fast(exp2_fast(ac2[j]) + 1.f), 1.f);
            th[12 + j] = fmaf(-2.f, recip_fast(exp2_fast(ac3[j]) + 1.f), 1.f);
        }

        // 7. exact-recurrence deltas + prefix -> Y_c
        const bool actd = (c <= 3) && (k + c < n);
        float dl[16];
        #pragma unroll
        for (int j = 0; j < 16; ++j)
            dl[j] = actd ? DT_C * (fcur[j] - th[j]) : 0.f;
        PFX3(dl);

        // 8. store y_{k+c} = yprev + Y_c (rows c=0..3)
        if (actd) {
            float* po = out + (size_t)(k + c) * stride + cbase;
            #pragma unroll
            for (int h = 0; h < 4; ++h) {
                float4 st;
                st.x = yprev[4 * h + 0] + dl[4 * h + 0];
                st.y = yprev[4 * h + 1] + dl[4 * h + 1];
                st.z = yprev[4 * h + 2] + dl[4 * h + 2];
                st.w = yprev[4 * h + 3] + dl[4 * h + 3];
                *reinterpret_cast<float4*>(po + 16 * h) = st;
            }
        }

        // 9. issue broadcasts for next round:
        //    Y_3 (new yprev increment) from row position 3, f32;
        //    preview tanh from position 4, f16x2-packed.
        //    ds_swizzle BitMode: lane' = (lane & 0x10) | pos.
        #pragma unroll
        for (int j = 0; j < 16; ++j)
            swY[j] = __builtin_amdgcn_ds_swizzle(__float_as_int(dl[j]), 0x0070);
        #pragma unroll
        for (int i = 0; i < 8; ++i)
            swT[i] = __builtin_amdgcn_ds_swizzle(
                pack_h2i(th[2 * i], th[2 * i + 1]), 0x0090);

        // 10. rotate forces
        #pragma unroll
        for (int j = 0; j < 16; ++j) fcur[j] = fnext[j];
    }
}

extern "C" void kernel_launch(void* const* d_in, const int* in_sizes, int n_in,
                              void* d_out, int out_size, void* d_ws, size_t ws_size,
                              hipStream_t stream) {
    const float* y0     = (const float*)d_in[0];   // (B, S)
    const float* forces = (const float*)d_in[1];   // (n, B, S)
    const float* W      = (const float*)d_in[2];   // (S, S)
    float* out = (float*)d_out;                    // (n, B, S)

    const int BS = in_sizes[0];       // B * S
    const int B  = BS / SDIM;         // 128
    const int n  = in_sizes[1] / BS;  // 65

    rnes_inv_kernel<<<B, SDIM, 0, stream>>>(y0, forces, W, out, n, B);
}